// Round 14
// baseline (464.082 us; speedup 1.0000x reference)
//
#include <hip/hip_runtime.h>
#include <cstdint>
#include <cstddef>

typedef __bf16 bf16;
typedef __attribute__((ext_vector_type(4))) float f32x4;
typedef __attribute__((ext_vector_type(8))) __bf16 bf16x8;
typedef __attribute__((ext_vector_type(4))) __bf16 bf16x4;

static __device__ __forceinline__ f32x4 mfma16(bf16x8 a, bf16x8 b, f32x4 c) {
    return __builtin_amdgcn_mfma_f32_16x16x32_bf16(a, b, c, 0, 0, 0);
}

#define GLOAD_LDS16(gsrc, ldst)                                              \
    __builtin_amdgcn_global_load_lds(                                        \
        (const __attribute__((address_space(1))) void*)(gsrc),               \
        (__attribute__((address_space(3))) void*)(ldst), 16, 0, 0)

// ---------------------------------------------------------------------------
// Fused weight transpose + cast (all 8 weights in ONE launch):
// Wt[n*K + k] = bf16(W[k*N + n]). Job table passed by value.
// ---------------------------------------------------------------------------
struct TransArgs {
    const float* W[8];
    bf16* Wt[8];
    int K[8];
    int N[8];
    int blk0[9];   // prefix offsets; blk0[8] = total blocks
};

__global__ __launch_bounds__(256)
void transpose_all(TransArgs a) {
    __shared__ float tile[32][33];
    const int b = blockIdx.x;
    int j = 0;
    #pragma unroll
    for (int i = 0; i < 7; ++i)
        if (b >= a.blk0[i + 1]) j = i + 1;
    const int rel = b - a.blk0[j];
    const int K = a.K[j], N = a.N[j];
    const int nxb = N >> 5;
    const int n0 = (rel % nxb) * 32, k0 = (rel / nxb) * 32;
    const float* W = a.W[j];
    bf16* Wt = a.Wt[j];
    const int tx = threadIdx.x & 31, ty = threadIdx.x >> 5;  // ty 0..7
    #pragma unroll
    for (int i = ty; i < 32; i += 8)
        tile[i][tx] = W[(size_t)(k0 + i) * N + n0 + tx];
    __syncthreads();
    #pragma unroll
    for (int i = ty; i < 32; i += 8)
        Wt[(size_t)(n0 + i) * K + k0 + tx] = (bf16)tile[tx][i];
}

// ---------------------------------------------------------------------------
// LayerNorm over 512 cols, fp32 in -> bf16 out. 1 wave per row, 4 rows/block.
// ---------------------------------------------------------------------------
__global__ __launch_bounds__(256)
void ln_kernel(const float* __restrict__ x, const float* __restrict__ g,
               const float* __restrict__ b, bf16* __restrict__ out) {
    const int row = blockIdx.x * 4 + (threadIdx.x >> 6);
    const int lane = threadIdx.x & 63;
    const float* p = x + (size_t)row * 512 + lane * 8;
    const float4 a0 = *(const float4*)p;
    const float4 a1 = *(const float4*)(p + 4);
    float vx[8] = {a0.x, a0.y, a0.z, a0.w, a1.x, a1.y, a1.z, a1.w};
    float s = 0.f, ss = 0.f;
    #pragma unroll
    for (int k = 0; k < 8; ++k) { s += vx[k]; ss += vx[k] * vx[k]; }
    #pragma unroll
    for (int m = 1; m < 64; m <<= 1) {
        s  += __shfl_xor(s, m);
        ss += __shfl_xor(ss, m);
    }
    const float mean = s * (1.0f / 512.0f);
    const float var  = ss * (1.0f / 512.0f) - mean * mean;
    const float inv  = rsqrtf(var + 1e-5f);
    const int c0 = lane * 8;
    const float4 g0 = *(const float4*)&g[c0], g1 = *(const float4*)&g[c0 + 4];
    const float4 b0 = *(const float4*)&b[c0], b1 = *(const float4*)&b[c0 + 4];
    const float gv[8] = {g0.x, g0.y, g0.z, g0.w, g1.x, g1.y, g1.z, g1.w};
    const float bv[8] = {b0.x, b0.y, b0.z, b0.w, b1.x, b1.y, b1.z, b1.w};
    bf16x8 o;
    #pragma unroll
    for (int k = 0; k < 8; ++k)
        o[k] = (bf16)((vx[k] - mean) * inv * gv[k] + bv[k]);
    *(bf16x8*)&out[(size_t)row * 512 + c0] = o;
}

// ---------------------------------------------------------------------------
// GEMM: C[M,N] = A[M,K] bf16 x Bt[N,K]^T bf16. Tile 128xTN, BK=32, 8 waves
// (512 thr), wave grid 2M x 4N -> per-wave 64 x (TN/8). __launch_bounds__
// (512,8): 32 waves/CU.
//   TN=128 (QKV/FC1): acc[4][2], the R13-verified path.
//   TN=64  (proj/FC2): acc[4][1], grid doubles (8 x 128 = 1024 blocks) ->
//     full-occupancy for the N=512 GEMMs that were grid-limited to 16
//     waves/CU (R13 ledger: occupancy dominates at this structure).
// HYBRID K: KT>0 -> fully-unrolled static-K (K=512 win); KT==0 -> runtime
// loop (K=2048: static unroll regressed twice). Double-buffered linear LDS
// via global_load_lds(16B) + source slot swizzle, one barrier per K-step,
// XCD-chunked block swizzle. Vectorized epilogues via per-wave LDS bounce.
// EPI 0: bf16. EPI 1: +bias +res(fp32), fp32. EPI 2: +bias, GELU, bf16.
// ---------------------------------------------------------------------------
template <int EPI, int KT, int TN>
__global__ __launch_bounds__(512, 8)
void gemm_bt(const bf16* __restrict__ A, const bf16* __restrict__ Bt,
             int N, int Krt, const float* __restrict__ bias,
             const float* __restrict__ res, float* __restrict__ outf,
             bf16* __restrict__ outh) {
    static_assert(TN == 128 || EPI == 1, "TN=64 only with fp32 epilogue");
    constexpr int NJ = (TN == 128) ? 2 : 1;          // B-frags per wave
    constexpr int SMEM_ELEMS = 8192 + 2 * TN * 32;   // A dbuf + B dbuf
    const int K = (KT > 0) ? KT : Krt;
    __shared__ __align__(16) bf16 smem[SMEM_ELEMS];
    auto lsA = [&](int buf) { return smem + buf * 4096; };
    auto lsB = [&](int buf) { return smem + 8192 + buf * (TN * 32); };
    const int nx = gridDim.x;
    const int nwg = nx * gridDim.y;
    const int flat = blockIdx.y * nx + blockIdx.x;
    const int cpx = nwg >> 3;
    const int bswz = (flat & 7) * cpx + (flat >> 3);
    const int bn = bswz % nx, bm = bswz / nx;

    const int tid = threadIdx.x, lane = tid & 63, wv = tid >> 6;   // wv 0..7
    const int wr = wv >> 2, wc = wv & 3;        // 2M x 4N wave grid
    const int l15 = lane & 15, lg = lane >> 4;
    const size_t abase = (size_t)bm * 128 * K;
    const size_t bbase = (size_t)bn * TN * K;
    // staging: wave wv stages 16-row chunk wv of A (always) and of B
    // (TN=128: chunk wv; TN=64: only waves 0-3 have a B chunk).
    const int sr = wv * 16 + (lane >> 2);        // row within tile
    const int ks = ((lane & 3) ^ ((sr >> 1) & 3)) * 8;  // swizzled k-offset
    const bf16* aSrc = &A[abase + (size_t)sr * K + ks];
    const bf16* bSrc = &Bt[bbase + (size_t)sr * K + ks];
    const bool doB = (TN == 128) || (wv < 4);

    f32x4 acc[4][NJ] = {};

    auto stage = [&](int buf, int kt) {
        GLOAD_LDS16(aSrc + kt, lsA(buf) + wv * 512);
        if (doB) GLOAD_LDS16(bSrc + kt, lsB(buf) + wv * 512);
    };
    auto compute = [&](int buf) {
        bf16x8 af[4], bfr[NJ];
        #pragma unroll
        for (int i = 0; i < 4; ++i) {
            const int r = wr * 64 + i * 16 + l15;
            af[i] = *(const bf16x8*)
                (lsA(buf) + r * 32 + ((lg ^ ((r >> 1) & 3)) * 8));
        }
        #pragma unroll
        for (int j = 0; j < NJ; ++j) {
            const int r = wc * (16 * NJ) + j * 16 + l15;
            bfr[j] = *(const bf16x8*)
                (lsB(buf) + r * 32 + ((lg ^ ((r >> 1) & 3)) * 8));
        }
        #pragma unroll
        for (int i = 0; i < 4; ++i)
            #pragma unroll
            for (int j = 0; j < NJ; ++j)
                acc[i][j] = mfma16(af[i], bfr[j], acc[i][j]);
    };

    if constexpr (KT > 0) {
        constexpr int NK = KT >> 5;        // 16 for K=512
        stage(0, 0);
        __syncthreads();
        #pragma unroll
        for (int t = 0; t < NK - 1; ++t) {
            stage((t + 1) & 1, (t + 1) * 32);   // consts fold to immediates
            compute(t & 1);
            __syncthreads();
        }
        compute((NK - 1) & 1);
        __syncthreads();
    } else {
        const int NK = K >> 5;             // runtime loop (R9 codegen)
        stage(0, 0);
        __syncthreads();
        int cur = 0;
        for (int t = 0; t < NK - 1; ++t) {
            stage(cur ^ 1, (t + 1) * 32);
            compute(cur);
            __syncthreads();
            cur ^= 1;
        }
        compute(cur);
        __syncthreads();
    }

    // ---- vectorized epilogue via per-wave LDS bounce ----
    const int orow = bm * 128 + wr * 64;
    const int ocol = bn * TN + wc * (16 * NJ);
    if constexpr (NJ == 2) {
        float* lsW = (float*)smem + wv * 1024;   // [16][36]
        #pragma unroll
        for (int i = 0; i < 4; ++i) {
            #pragma unroll
            for (int r = 0; r < 4; ++r)
                #pragma unroll
                for (int j = 0; j < 2; ++j)
                    lsW[(lg * 4 + r) * 36 + j * 16 + l15] = acc[i][j][r];
            __builtin_amdgcn_s_waitcnt(0);
            if constexpr (EPI == 0 || EPI == 2) {
                const int rl = lane >> 2, c8 = (lane & 3) * 8;
                const float4 v0 = *(const float4*)&lsW[rl * 36 + c8];
                const float4 v1 = *(const float4*)&lsW[rl * 36 + c8 + 4];
                float vv[8] = {v0.x, v0.y, v0.z, v0.w, v1.x, v1.y, v1.z, v1.w};
                if constexpr (EPI == 2) {
                    const float4 bb0 = *(const float4*)&bias[ocol + c8];
                    const float4 bb1 = *(const float4*)&bias[ocol + c8 + 4];
                    const float bv[8] = {bb0.x, bb0.y, bb0.z, bb0.w,
                                         bb1.x, bb1.y, bb1.z, bb1.w};
                    #pragma unroll
                    for (int e = 0; e < 8; ++e) {
                        const float t = vv[e] + bv[e];
                        vv[e] = 0.5f * t * (1.0f + erff(t * 0.70710678118f));
                    }
                }
                bf16x8 o;
                #pragma unroll
                for (int e = 0; e < 8; ++e) o[e] = (bf16)vv[e];
                *(bf16x8*)&outh[(size_t)(orow + i * 16 + rl) * N + ocol + c8] = o;
            } else {
                const int c4 = (lane & 7) * 4;
                const float4 bb = *(const float4*)&bias[ocol + c4];
                #pragma unroll
                for (int ii = 0; ii < 2; ++ii) {
                    const int rl = ii * 8 + (lane >> 3);
                    const size_t gro = (size_t)(orow + i * 16 + rl) * N + ocol + c4;
                    float4 v = *(const float4*)&lsW[rl * 36 + c4];
                    const float4 rr = *(const float4*)&res[gro];
                    v.x += bb.x + rr.x; v.y += bb.y + rr.y;
                    v.z += bb.z + rr.z; v.w += bb.w + rr.w;
                    *(float4*)&outf[gro] = v;
                }
            }
        }
    } else {
        // NJ==1 (EPI1 only): per-wave 64x16; bounce [16][20]; 1 float4/lane.
        float* lsW = (float*)smem + wv * 320;
        const int rl = lane >> 2, c4 = (lane & 3) * 4;
        const float4 bb = *(const float4*)&bias[ocol + c4];
        #pragma unroll
        for (int i = 0; i < 4; ++i) {
            #pragma unroll
            for (int r = 0; r < 4; ++r)
                lsW[(lg * 4 + r) * 20 + l15] = acc[i][0][r];
            __builtin_amdgcn_s_waitcnt(0);
            const size_t gro = (size_t)(orow + i * 16 + rl) * N + ocol + c4;
            float4 v = *(const float4*)&lsW[rl * 20 + c4];
            const float4 rr = *(const float4*)&res[gro];
            v.x += bb.x + rr.x; v.y += bb.y + rr.y;
            v.z += bb.z + rr.z; v.w += bb.w + rr.w;
            *(float4*)&outf[gro] = v;
            __builtin_amdgcn_s_waitcnt(0);  // next i rewrites same region
        }
    }
}

// ---------------------------------------------------------------------------
// Attention stats: block = (window w = bid>>2, head quad q = bid&3), one head
// per wave. Partial |QK^T + 0.1*rpe| sums -> Mraw4[w*4+q] (deterministic).
// ---------------------------------------------------------------------------
__global__ __launch_bounds__(256)
void attn_stats(const bf16* __restrict__ qkv, const float* __restrict__ rpe,
                float* __restrict__ Mraw4, int idx) {
    __shared__ float lsum[4];
    const int bid = blockIdx.x;
    const int w = bid >> 2;
    const int tid = threadIdx.x, lane = tid & 63, wv = tid >> 6;
    const int h = (bid & 3) * 4 + wv;
    const int l15 = lane & 15, lg = lane >> 4;
    const long gbase = (idx == 0) ? (long)w * 64 : ((long)(w >> 6) * 4096 + (w & 63));
    const long gstride = (idx == 0) ? 1 : 64;
    bf16x8 kf[4];
    #pragma unroll
    for (int i = 0; i < 4; ++i) {
        const long gs = gbase + (long)(i * 16 + l15) * gstride;
        kf[i] = *(const bf16x8*)&qkv[gs * 1536 + 512 + h * 32 + lg * 8];
    }
    const float* rh = rpe + h * 4096;
    float asum = 0.f;
    #pragma unroll
    for (int mi = 0; mi < 4; ++mi) {
        const long gs = gbase + (long)(mi * 16 + l15) * gstride;
        const bf16x8 qf = *(const bf16x8*)&qkv[gs * 1536 + h * 32 + lg * 8];
        f32x4 sc[4] = {};
        #pragma unroll
        for (int ni = 0; ni < 4; ++ni) sc[ni] = mfma16(qf, kf[ni], sc[ni]);
        #pragma unroll
        for (int r = 0; r < 4; ++r) {
            const int srow = mi * 16 + lg * 4 + r;
            #pragma unroll
            for (int ni = 0; ni < 4; ++ni)
                asum += fabsf(sc[ni][r] + 0.1f * rh[srow * 64 + ni * 16 + l15]);
        }
    }
    #pragma unroll
    for (int m = 1; m < 64; m <<= 1) asum += __shfl_xor(asum, m);
    if (lane == 0) lsum[wv] = asum;
    __syncthreads();
    if (tid == 0) Mraw4[bid] = lsum[0] + lsum[1] + lsum[2] + lsum[3];
}

// M[w] = max( (sum(Mraw4[w*4..+3])/65536) / max_w(...), 0.5 )
__global__ __launch_bounds__(256)
void mcalc(const float* __restrict__ Mraw4, float* __restrict__ Mv) {
    __shared__ float red[4];
    const int t = threadIdx.x, lane = t & 63;
    const float v = (Mraw4[t * 4] + Mraw4[t * 4 + 1] + Mraw4[t * 4 + 2] +
                     Mraw4[t * 4 + 3]) * (1.0f / 65536.0f);
    float m = v;
    #pragma unroll
    for (int msk = 1; msk < 64; msk <<= 1) m = fmaxf(m, __shfl_xor(m, msk));
    if (lane == 0) red[t >> 6] = m;
    __syncthreads();
    const float mm = fmaxf(fmaxf(red[0], red[1]), fmaxf(red[2], red[3]));
    Mv[t] = fmaxf(v / mm, 0.5f);
}

// ---------------------------------------------------------------------------
// Attention apply: block = (window, head quad), one head per wave.
// QK^T (MFMA) -> +0.1*rpe -> row L2-norm -> 1-cos -> *M -> P in swizzled LDS
// -> PV via MFMA with V^T in swizzled LDS -> unpartition + masked residual.
// ---------------------------------------------------------------------------
__global__ __launch_bounds__(256)
void attn_apply(const bf16* __restrict__ qkv, const float* __restrict__ rpe,
                const float* __restrict__ Mv, const float* __restrict__ xin,
                bf16* __restrict__ attout, int idx) {
    __shared__ __align__(16) bf16 lsP[4][64 * 64];
    __shared__ __align__(16) bf16 lsVt[4][32 * 64];
    const int bid = blockIdx.x;
    const int w = bid >> 2;
    const int tid = threadIdx.x, lane = tid & 63, wv = tid >> 6;
    const int h = (bid & 3) * 4 + wv;
    const int l15 = lane & 15, lg = lane >> 4;
    const long gbase = (idx == 0) ? (long)w * 64 : ((long)(w >> 6) * 4096 + (w & 63));
    const long gstride = (idx == 0) ? 1 : 64;
    const float Mw = Mv[w];
    bf16* P  = lsP[wv];
    bf16* Vt = lsVt[wv];

    {
        const int d4 = (lane & 7) * 4;
        #pragma unroll
        for (int it = 0; it < 8; ++it) {
            const int t = it * 8 + (lane >> 3);
            const bf16x4 v = *(const bf16x4*)
                &qkv[(gbase + (long)t * gstride) * 1536 + 1024 + h * 32 + d4];
            #pragma unroll
            for (int e = 0; e < 4; ++e) {
                const int d = d4 + e;
                Vt[d * 64 + (t ^ ((d & 7) * 8))] = v[e];
            }
        }
    }
    bf16x8 kf[4];
    #pragma unroll
    for (int i = 0; i < 4; ++i) {
        const long gs = gbase + (long)(i * 16 + l15) * gstride;
        kf[i] = *(const bf16x8*)&qkv[gs * 1536 + 512 + h * 32 + lg * 8];
    }
    const float* rh = rpe + h * 4096;
    #pragma unroll
    for (int mi = 0; mi < 4; ++mi) {
        const long gs = gbase + (long)(mi * 16 + l15) * gstride;
        const bf16x8 qf = *(const bf16x8*)&qkv[gs * 1536 + h * 32 + lg * 8];
        f32x4 sc[4] = {};
        #pragma unroll
        for (int ni = 0; ni < 4; ++ni) sc[ni] = mfma16(qf, kf[ni], sc[ni]);
        #pragma unroll
        for (int r = 0; r < 4; ++r) {
            const int srow = mi * 16 + lg * 4 + r;
            float vv[4], ssq = 0.f;
            #pragma unroll
            for (int ni = 0; ni < 4; ++ni) {
                const float v = sc[ni][r] + 0.1f * rh[srow * 64 + ni * 16 + l15];
                vv[ni] = v;
                ssq += v * v;
            }
            ssq += __shfl_xor(ssq, 1);
            ssq += __shfl_xor(ssq, 2);
            ssq += __shfl_xor(ssq, 4);
            ssq += __shfl_xor(ssq, 8);
            const float is = 1.0f / fmaxf(sqrtf(ssq), 1e-12f);
            #pragma unroll
            for (int ni = 0; ni < 4; ++ni) {
                const float v = (1.0f - __cosf(vv[ni] * is * 1.57079632679f)) * Mw;
                const int col = ni * 16 + l15;
                P[srow * 64 + (col ^ ((srow & 7) * 8))] = (bf16)v;
            }
        }
    }
    f32x4 acc[4][2] = {};
    #pragma unroll
    for (int kk = 0; kk < 2; ++kk) {
        bf16x8 bfr[2];
        #pragma unroll
        for (int dj = 0; dj < 2; ++dj) {
            const int d = dj * 16 + l15;
            bfr[dj] = *(const bf16x8*)&Vt[d * 64 + ((kk * 32 + lg * 8) ^ ((d & 7) * 8))];
        }
        #pragma unroll
        for (int mi = 0; mi < 4; ++mi) {
            const int s = mi * 16 + l15;
            const bf16x8 af = *(const bf16x8*)&P[s * 64 + ((kk * 32 + lg * 8) ^ ((s & 7) * 8))];
            #pragma unroll
            for (int dj = 0; dj < 2; ++dj)
                acc[mi][dj] = mfma16(af, bfr[dj], acc[mi][dj]);
        }
    }
    #pragma unroll
    for (int mi = 0; mi < 4; ++mi) {
        #pragma unroll
        for (int r = 0; r < 4; ++r) {
            const int s = mi * 16 + lg * 4 + r;
            const long gg = gbase + (long)s * gstride;
            const float rm = 1.0f - Mv[(int)(gg >> 6)];
            #pragma unroll
            for (int dj = 0; dj < 2; ++dj) {
                const int d = dj * 16 + l15;
                const size_t oidx = (size_t)gg * 512 + h * 32 + d;
                attout[oidx] = (bf16)(acc[mi][dj][r] + xin[oidx] * rm);
            }
        }
    }
}

// ---------------------------------------------------------------------------
// Host-side orchestration
// ---------------------------------------------------------------------------
extern "C" void kernel_launch(void* const* d_in, const int* in_sizes, int n_in,
                              void* d_out, int out_size, void* d_ws, size_t ws_size,
                              hipStream_t stream) {
    const float* x    = (const float*)d_in[0];
    const float* rpe0 = (const float*)d_in[1];
    const float* rpe1 = (const float*)d_in[2];
    auto W = [&](int i) { return (const float*)d_in[i]; };

    char* ws = (char*)d_ws;
    size_t off = 0;
    auto alloc = [&](size_t bytes) {
        void* p = ws + off;
        off += (bytes + 255) & ~(size_t)255;
        return p;
    };
    bf16 *wqkvT[2], *wprojT[2], *wfc1T[2], *wfc2T[2];
    for (int b = 0; b < 2; ++b) {
        wqkvT[b] = (bf16*)alloc((size_t)1536 * 512 * 2);
        wprojT[b] = (bf16*)alloc((size_t)512 * 512 * 2);
        wfc1T[b] = (bf16*)alloc((size_t)2048 * 512 * 2);
        wfc2T[b] = (bf16*)alloc((size_t)512 * 2048 * 2);
    }
    bf16* IMG = (bf16*)alloc((size_t)16384 * 512 * 2);
    bf16* QKV = (bf16*)alloc((size_t)16384 * 1536 * 2);
    bf16* ATT = (bf16*)alloc((size_t)16384 * 512 * 2);
    bf16* H1  = QKV;  // fc1 output [16384,2048] overlays QKV+ATT (both dead)
    float* X1    = (float*)alloc((size_t)16384 * 512 * 4);
    float* Mraw4 = (float*)alloc(1024 * 4);
    float* Mv    = (float*)alloc(256 * 4);
    float* XMID  = (float*)d_out;  // x after attention residual (fp32 spine)

    // ---- fused weight transpose: all 8 in one launch ----
    TransArgs ta;
    const int widx[8] = {5, 6, 10, 12, 16, 17, 21, 23};
    bf16* wdst[8] = {wqkvT[0], wprojT[0], wfc1T[0], wfc2T[0],
                     wqkvT[1], wprojT[1], wfc1T[1], wfc2T[1]};
    const int wk[8] = {512, 512, 512, 2048, 512, 512, 512, 2048};
    const int wn[8] = {1536, 512, 2048, 512, 1536, 512, 2048, 512};
    int acc_b = 0;
    for (int i = 0; i < 8; ++i) {
        ta.W[i] = W(widx[i]);
        ta.Wt[i] = wdst[i];
        ta.K[i] = wk[i];
        ta.N[i] = wn[i];
        ta.blk0[i] = acc_b;
        acc_b += (wn[i] / 32) * (wk[i] / 32);
    }
    ta.blk0[8] = acc_b;   // 6144
    transpose_all<<<acc_b, 256, 0, stream>>>(ta);

    for (int b = 0; b < 2; ++b) {
        const float* xin = (b == 0) ? x : X1;
        const float* rpe = (b == 0) ? rpe0 : rpe1;
        const int base = (b == 0) ? 3 : 14;
        const float* ln1g = W(base + 0);
        const float* ln1b = W(base + 1);
        const float* bproj = W(base + 4);
        const float* ln2g = W(base + 5);
        const float* ln2b = W(base + 6);
        const float* bfc1 = W(base + 8);
        const float* bfc2 = W(base + 10);

        // 1. LN1: xin -> IMG (bf16)
        ln_kernel<<<4096, 256, 0, stream>>>(xin, ln1g, ln1b, IMG);
        // 2. QKV GEMM (K=512 static, TN=128): IMG @ wqkv -> QKV (bf16)
        gemm_bt<0, 512, 128><<<dim3(12, 128), 512, 0, stream>>>(
            IMG, wqkvT[b], 1536, 512, nullptr, nullptr, nullptr, QKV);
        // 3-4. gating scalar M per window
        attn_stats<<<1024, 256, 0, stream>>>(QKV, rpe, Mraw4, b);
        mcalc<<<1, 256, 0, stream>>>(Mraw4, Mv);
        // 5. attention apply -> ATT (bf16), includes masked residual
        attn_apply<<<1024, 256, 0, stream>>>(QKV, rpe, Mv, xin, ATT, b);
        // 6. proj GEMM (K=512 static, TN=64): ATT @ wproj + bproj + xin
        gemm_bt<1, 512, 64><<<dim3(8, 128), 512, 0, stream>>>(
            ATT, wprojT[b], 512, 512, bproj, xin, XMID, nullptr);
        // 7. LN2: XMID -> IMG (bf16)
        ln_kernel<<<4096, 256, 0, stream>>>(XMID, ln2g, ln2b, IMG);
        // 8. FC1 + exact GELU (K=512 static, TN=128): IMG @ wfc1 -> H1
        gemm_bt<2, 512, 128><<<dim3(16, 128), 512, 0, stream>>>(
            IMG, wfc1T[b], 2048, 512, bfc1, nullptr, nullptr, H1);
        // 9. FC2 (K=2048 runtime, TN=64): H1 @ wfc2 + bfc2 + XMID
        gemm_bt<1, 0, 64><<<dim3(8, 128), 512, 0, stream>>>(
            H1, wfc2T[b], 512, 2048, bfc2, XMID, (b == 0) ? X1 : XMID, nullptr);
    }
    (void)in_sizes; (void)n_in; (void)out_size; (void)ws_size;
}

// Round 15
// 436.086 us; speedup vs baseline: 1.0642x; 1.0642x over previous
//
#include <hip/hip_runtime.h>
#include <cstdint>
#include <cstddef>

typedef __bf16 bf16;
typedef __attribute__((ext_vector_type(4))) float f32x4;
typedef __attribute__((ext_vector_type(8))) __bf16 bf16x8;
typedef __attribute__((ext_vector_type(4))) __bf16 bf16x4;

static __device__ __forceinline__ f32x4 mfma16(bf16x8 a, bf16x8 b, f32x4 c) {
    return __builtin_amdgcn_mfma_f32_16x16x32_bf16(a, b, c, 0, 0, 0);
}

#define GLOAD_LDS16(gsrc, ldst)                                              \
    __builtin_amdgcn_global_load_lds(                                        \
        (const __attribute__((address_space(1))) void*)(gsrc),               \
        (__attribute__((address_space(3))) void*)(ldst), 16, 0, 0)

// ---------------------------------------------------------------------------
// Fused weight transpose + cast (all 8 weights in ONE launch):
// Wt[n*K + k] = bf16(W[k*N + n]). Job table passed by value.
// ---------------------------------------------------------------------------
struct TransArgs {
    const float* W[8];
    bf16* Wt[8];
    int K[8];
    int N[8];
    int blk0[9];   // prefix offsets; blk0[8] = total blocks
};

__global__ __launch_bounds__(256)
void transpose_all(TransArgs a) {
    __shared__ float tile[32][33];
    const int b = blockIdx.x;
    int j = 0;
    #pragma unroll
    for (int i = 0; i < 7; ++i)
        if (b >= a.blk0[i + 1]) j = i + 1;
    const int rel = b - a.blk0[j];
    const int K = a.K[j], N = a.N[j];
    const int nxb = N >> 5;
    const int n0 = (rel % nxb) * 32, k0 = (rel / nxb) * 32;
    const float* W = a.W[j];
    bf16* Wt = a.Wt[j];
    const int tx = threadIdx.x & 31, ty = threadIdx.x >> 5;  // ty 0..7
    #pragma unroll
    for (int i = ty; i < 32; i += 8)
        tile[i][tx] = W[(size_t)(k0 + i) * N + n0 + tx];
    __syncthreads();
    #pragma unroll
    for (int i = ty; i < 32; i += 8)
        Wt[(size_t)(n0 + i) * K + k0 + tx] = (bf16)tile[tx][i];
}

// ---------------------------------------------------------------------------
// LayerNorm over 512 cols, fp32 in -> bf16 out. 1 wave per row, 4 rows/block.
// ---------------------------------------------------------------------------
__global__ __launch_bounds__(256)
void ln_kernel(const float* __restrict__ x, const float* __restrict__ g,
               const float* __restrict__ b, bf16* __restrict__ out) {
    const int row = blockIdx.x * 4 + (threadIdx.x >> 6);
    const int lane = threadIdx.x & 63;
    const float* p = x + (size_t)row * 512 + lane * 8;
    const float4 a0 = *(const float4*)p;
    const float4 a1 = *(const float4*)(p + 4);
    float vx[8] = {a0.x, a0.y, a0.z, a0.w, a1.x, a1.y, a1.z, a1.w};
    float s = 0.f, ss = 0.f;
    #pragma unroll
    for (int k = 0; k < 8; ++k) { s += vx[k]; ss += vx[k] * vx[k]; }
    #pragma unroll
    for (int m = 1; m < 64; m <<= 1) {
        s  += __shfl_xor(s, m);
        ss += __shfl_xor(ss, m);
    }
    const float mean = s * (1.0f / 512.0f);
    const float var  = ss * (1.0f / 512.0f) - mean * mean;
    const float inv  = rsqrtf(var + 1e-5f);
    const int c0 = lane * 8;
    const float4 g0 = *(const float4*)&g[c0], g1 = *(const float4*)&g[c0 + 4];
    const float4 b0 = *(const float4*)&b[c0], b1 = *(const float4*)&b[c0 + 4];
    const float gv[8] = {g0.x, g0.y, g0.z, g0.w, g1.x, g1.y, g1.z, g1.w};
    const float bv[8] = {b0.x, b0.y, b0.z, b0.w, b1.x, b1.y, b1.z, b1.w};
    bf16x8 o;
    #pragma unroll
    for (int k = 0; k < 8; ++k)
        o[k] = (bf16)((vx[k] - mean) * inv * gv[k] + bv[k]);
    *(bf16x8*)&out[(size_t)row * 512 + c0] = o;
}

// ---------------------------------------------------------------------------
// GEMM: C[M,N] = A[M,K] bf16 x Bt[N,K]^T bf16. 128x128 tile, BK=32,
// 8 waves (512 thr), 2Mx4N wave grid -> per-wave 64x32 output (acc[4][2],
// 32 VGPR). __launch_bounds__(512,8): 32 waves/CU (occ ~75% verified).
// R13-verified best config (R14's TN=64 for N=512 GEMMs regressed: halving
// per-wave MFMA per K-step while keeping the same staging+barrier overhead
// loses more than the occupancy gain -- reverted).
// HYBRID K policy: KT>0 -> fully-unrolled static-K (K=512 win, address
// folding); KT==0 -> runtime loop (K=2048: static unroll regressed twice).
// Double-buffered 32KB linear LDS via global_load_lds(16B) + source slot
// swizzle, one barrier per K-step, XCD-chunked block swizzle. Epilogue via
// per-wave [16][36] LDS bounce, vectorized stores.
// EPI 0: bf16. EPI 1: +bias +res(fp32), fp32. EPI 2: +bias, GELU, bf16.
// ---------------------------------------------------------------------------
template <int EPI, int KT>
__global__ __launch_bounds__(512, 8)
void gemm_bt(const bf16* __restrict__ A, const bf16* __restrict__ Bt,
             int N, int Krt, const float* __restrict__ bias,
             const float* __restrict__ res, float* __restrict__ outf,
             bf16* __restrict__ outh) {
    const int K = (KT > 0) ? KT : Krt;
    __shared__ __align__(16) bf16 smem[16384];   // 32 KB
    auto lsA = [&](int buf) { return smem + buf * 4096; };
    auto lsB = [&](int buf) { return smem + 8192 + buf * 4096; };
    const int nx = gridDim.x;
    const int nwg = nx * gridDim.y;
    const int flat = blockIdx.y * nx + blockIdx.x;
    const int cpx = nwg >> 3;
    const int bswz = (flat & 7) * cpx + (flat >> 3);
    const int bn = bswz % nx, bm = bswz / nx;

    const int tid = threadIdx.x, lane = tid & 63, wv = tid >> 6;   // wv 0..7
    const int wr = wv >> 2, wc = wv & 3;        // 2M x 4N wave grid
    const int l15 = lane & 15, lg = lane >> 4;
    const size_t abase = (size_t)bm * 128 * K;
    const size_t bbase = (size_t)bn * 128 * K;
    // staging: wave wv stages 16-row chunk wv of A and of B (1 load each).
    const int sr = wv * 16 + (lane >> 2);        // global tile row
    const int ks = ((lane & 3) ^ ((sr >> 1) & 3)) * 8;  // swizzled k-offset
    const bf16* aSrc = &A[abase + (size_t)sr * K + ks];
    const bf16* bSrc = &Bt[bbase + (size_t)sr * K + ks];

    f32x4 acc[4][2] = {};

    auto stage = [&](int buf, int kt) {   // 2 loads/wave
        GLOAD_LDS16(aSrc + kt, lsA(buf) + wv * 512);
        GLOAD_LDS16(bSrc + kt, lsB(buf) + wv * 512);
    };
    auto compute = [&](int buf) {
        bf16x8 af[4], bfr[2];
        #pragma unroll
        for (int i = 0; i < 4; ++i) {
            const int r = wr * 64 + i * 16 + l15;
            af[i] = *(const bf16x8*)
                (lsA(buf) + r * 32 + ((lg ^ ((r >> 1) & 3)) * 8));
        }
        #pragma unroll
        for (int j = 0; j < 2; ++j) {
            const int r = wc * 32 + j * 16 + l15;
            bfr[j] = *(const bf16x8*)
                (lsB(buf) + r * 32 + ((lg ^ ((r >> 1) & 3)) * 8));
        }
        #pragma unroll
        for (int i = 0; i < 4; ++i)
            #pragma unroll
            for (int j = 0; j < 2; ++j)
                acc[i][j] = mfma16(af[i], bfr[j], acc[i][j]);
    };

    if constexpr (KT > 0) {
        constexpr int NK = KT >> 5;        // 16 for K=512
        stage(0, 0);
        __syncthreads();
        #pragma unroll
        for (int t = 0; t < NK - 1; ++t) {
            stage((t + 1) & 1, (t + 1) * 32);   // consts fold to immediates
            compute(t & 1);
            __syncthreads();
        }
        compute((NK - 1) & 1);
        __syncthreads();
    } else {
        const int NK = K >> 5;             // runtime loop (R9 codegen)
        stage(0, 0);
        __syncthreads();
        int cur = 0;
        for (int t = 0; t < NK - 1; ++t) {
            stage(cur ^ 1, (t + 1) * 32);
            compute(cur);
            __syncthreads();
            cur ^= 1;
        }
        compute(cur);
        __syncthreads();
    }

    // ---- vectorized epilogue via per-wave LDS bounce ----
    float* lsW = (float*)smem + wv * 1024;   // [16][36]
    const int orow = bm * 128 + wr * 64;
    const int ocol = bn * 128 + wc * 32;
    #pragma unroll
    for (int i = 0; i < 4; ++i) {
        #pragma unroll
        for (int r = 0; r < 4; ++r)
            #pragma unroll
            for (int j = 0; j < 2; ++j)
                lsW[(lg * 4 + r) * 36 + j * 16 + l15] = acc[i][j][r];
        __builtin_amdgcn_s_waitcnt(0);   // lgkmcnt(0): same-wave visibility
        if constexpr (EPI == 0 || EPI == 2) {
            const int rl = lane >> 2, c8 = (lane & 3) * 8;
            const float4 v0 = *(const float4*)&lsW[rl * 36 + c8];
            const float4 v1 = *(const float4*)&lsW[rl * 36 + c8 + 4];
            float vv[8] = {v0.x, v0.y, v0.z, v0.w, v1.x, v1.y, v1.z, v1.w};
            if constexpr (EPI == 2) {
                const float4 bb0 = *(const float4*)&bias[ocol + c8];
                const float4 bb1 = *(const float4*)&bias[ocol + c8 + 4];
                const float bv[8] = {bb0.x, bb0.y, bb0.z, bb0.w,
                                     bb1.x, bb1.y, bb1.z, bb1.w};
                #pragma unroll
                for (int e = 0; e < 8; ++e) {
                    const float t = vv[e] + bv[e];
                    vv[e] = 0.5f * t * (1.0f + erff(t * 0.70710678118f));
                }
            }
            bf16x8 o;
            #pragma unroll
            for (int e = 0; e < 8; ++e) o[e] = (bf16)vv[e];
            *(bf16x8*)&outh[(size_t)(orow + i * 16 + rl) * N + ocol + c8] = o;
        } else {
            const int c4 = (lane & 7) * 4;
            const float4 bb = *(const float4*)&bias[ocol + c4];
            #pragma unroll
            for (int ii = 0; ii < 2; ++ii) {
                const int rl = ii * 8 + (lane >> 3);
                const size_t gro = (size_t)(orow + i * 16 + rl) * N + ocol + c4;
                float4 v = *(const float4*)&lsW[rl * 36 + c4];
                const float4 rr = *(const float4*)&res[gro];
                v.x += bb.x + rr.x; v.y += bb.y + rr.y;
                v.z += bb.z + rr.z; v.w += bb.w + rr.w;
                *(float4*)&outf[gro] = v;
            }
        }
    }
}

// ---------------------------------------------------------------------------
// Attention stats: block = (window w = bid>>2, head quad q = bid&3), one head
// per wave. Partial |QK^T + 0.1*rpe| sums -> Mraw4[w*4+q] (deterministic).
// ---------------------------------------------------------------------------
__global__ __launch_bounds__(256)
void attn_stats(const bf16* __restrict__ qkv, const float* __restrict__ rpe,
                float* __restrict__ Mraw4, int idx) {
    __shared__ float lsum[4];
    const int bid = blockIdx.x;
    const int w = bid >> 2;
    const int tid = threadIdx.x, lane = tid & 63, wv = tid >> 6;
    const int h = (bid & 3) * 4 + wv;
    const int l15 = lane & 15, lg = lane >> 4;
    const long gbase = (idx == 0) ? (long)w * 64 : ((long)(w >> 6) * 4096 + (w & 63));
    const long gstride = (idx == 0) ? 1 : 64;
    bf16x8 kf[4];
    #pragma unroll
    for (int i = 0; i < 4; ++i) {
        const long gs = gbase + (long)(i * 16 + l15) * gstride;
        kf[i] = *(const bf16x8*)&qkv[gs * 1536 + 512 + h * 32 + lg * 8];
    }
    const float* rh = rpe + h * 4096;
    float asum = 0.f;
    #pragma unroll
    for (int mi = 0; mi < 4; ++mi) {
        const long gs = gbase + (long)(mi * 16 + l15) * gstride;
        const bf16x8 qf = *(const bf16x8*)&qkv[gs * 1536 + h * 32 + lg * 8];
        f32x4 sc[4] = {};
        #pragma unroll
        for (int ni = 0; ni < 4; ++ni) sc[ni] = mfma16(qf, kf[ni], sc[ni]);
        #pragma unroll
        for (int r = 0; r < 4; ++r) {
            const int srow = mi * 16 + lg * 4 + r;
            #pragma unroll
            for (int ni = 0; ni < 4; ++ni)
                asum += fabsf(sc[ni][r] + 0.1f * rh[srow * 64 + ni * 16 + l15]);
        }
    }
    #pragma unroll
    for (int m = 1; m < 64; m <<= 1) asum += __shfl_xor(asum, m);
    if (lane == 0) lsum[wv] = asum;
    __syncthreads();
    if (tid == 0) Mraw4[bid] = lsum[0] + lsum[1] + lsum[2] + lsum[3];
}

// M[w] = max( (sum(Mraw4[w*4..+3])/65536) / max_w(...), 0.5 )
__global__ __launch_bounds__(256)
void mcalc(const float* __restrict__ Mraw4, float* __restrict__ Mv) {
    __shared__ float red[4];
    const int t = threadIdx.x, lane = t & 63;
    const float v = (Mraw4[t * 4] + Mraw4[t * 4 + 1] + Mraw4[t * 4 + 2] +
                     Mraw4[t * 4 + 3]) * (1.0f / 65536.0f);
    float m = v;
    #pragma unroll
    for (int msk = 1; msk < 64; msk <<= 1) m = fmaxf(m, __shfl_xor(m, msk));
    if (lane == 0) red[t >> 6] = m;
    __syncthreads();
    const float mm = fmaxf(fmaxf(red[0], red[1]), fmaxf(red[2], red[3]));
    Mv[t] = fmaxf(v / mm, 0.5f);
}

// ---------------------------------------------------------------------------
// Attention apply: block = (window, head quad), one head per wave.
// QK^T (MFMA) -> +0.1*rpe -> row L2-norm -> 1-cos -> *M -> P in swizzled LDS
// -> PV via MFMA with V^T in swizzled LDS -> unpartition + masked residual.
// ---------------------------------------------------------------------------
__global__ __launch_bounds__(256)
void attn_apply(const bf16* __restrict__ qkv, const float* __restrict__ rpe,
                const float* __restrict__ Mv, const float* __restrict__ xin,
                bf16* __restrict__ attout, int idx) {
    __shared__ __align__(16) bf16 lsP[4][64 * 64];
    __shared__ __align__(16) bf16 lsVt[4][32 * 64];
    const int bid = blockIdx.x;
    const int w = bid >> 2;
    const int tid = threadIdx.x, lane = tid & 63, wv = tid >> 6;
    const int h = (bid & 3) * 4 + wv;
    const int l15 = lane & 15, lg = lane >> 4;
    const long gbase = (idx == 0) ? (long)w * 64 : ((long)(w >> 6) * 4096 + (w & 63));
    const long gstride = (idx == 0) ? 1 : 64;
    const float Mw = Mv[w];
    bf16* P  = lsP[wv];
    bf16* Vt = lsVt[wv];

    {
        const int d4 = (lane & 7) * 4;
        #pragma unroll
        for (int it = 0; it < 8; ++it) {
            const int t = it * 8 + (lane >> 3);
            const bf16x4 v = *(const bf16x4*)
                &qkv[(gbase + (long)t * gstride) * 1536 + 1024 + h * 32 + d4];
            #pragma unroll
            for (int e = 0; e < 4; ++e) {
                const int d = d4 + e;
                Vt[d * 64 + (t ^ ((d & 7) * 8))] = v[e];
            }
        }
    }
    bf16x8 kf[4];
    #pragma unroll
    for (int i = 0; i < 4; ++i) {
        const long gs = gbase + (long)(i * 16 + l15) * gstride;
        kf[i] = *(const bf16x8*)&qkv[gs * 1536 + 512 + h * 32 + lg * 8];
    }
    const float* rh = rpe + h * 4096;
    #pragma unroll
    for (int mi = 0; mi < 4; ++mi) {
        const long gs = gbase + (long)(mi * 16 + l15) * gstride;
        const bf16x8 qf = *(const bf16x8*)&qkv[gs * 1536 + h * 32 + lg * 8];
        f32x4 sc[4] = {};
        #pragma unroll
        for (int ni = 0; ni < 4; ++ni) sc[ni] = mfma16(qf, kf[ni], sc[ni]);
        #pragma unroll
        for (int r = 0; r < 4; ++r) {
            const int srow = mi * 16 + lg * 4 + r;
            float vv[4], ssq = 0.f;
            #pragma unroll
            for (int ni = 0; ni < 4; ++ni) {
                const float v = sc[ni][r] + 0.1f * rh[srow * 64 + ni * 16 + l15];
                vv[ni] = v;
                ssq += v * v;
            }
            ssq += __shfl_xor(ssq, 1);
            ssq += __shfl_xor(ssq, 2);
            ssq += __shfl_xor(ssq, 4);
            ssq += __shfl_xor(ssq, 8);
            const float is = 1.0f / fmaxf(sqrtf(ssq), 1e-12f);
            #pragma unroll
            for (int ni = 0; ni < 4; ++ni) {
                const float v = (1.0f - __cosf(vv[ni] * is * 1.57079632679f)) * Mw;
                const int col = ni * 16 + l15;
                P[srow * 64 + (col ^ ((srow & 7) * 8))] = (bf16)v;
            }
        }
    }
    f32x4 acc[4][2] = {};
    #pragma unroll
    for (int kk = 0; kk < 2; ++kk) {
        bf16x8 bfr[2];
        #pragma unroll
        for (int dj = 0; dj < 2; ++dj) {
            const int d = dj * 16 + l15;
            bfr[dj] = *(const bf16x8*)&Vt[d * 64 + ((kk * 32 + lg * 8) ^ ((d & 7) * 8))];
        }
        #pragma unroll
        for (int mi = 0; mi < 4; ++mi) {
            const int s = mi * 16 + l15;
            const bf16x8 af = *(const bf16x8*)&P[s * 64 + ((kk * 32 + lg * 8) ^ ((s & 7) * 8))];
            #pragma unroll
            for (int dj = 0; dj < 2; ++dj)
                acc[mi][dj] = mfma16(af, bfr[dj], acc[mi][dj]);
        }
    }
    #pragma unroll
    for (int mi = 0; mi < 4; ++mi) {
        #pragma unroll
        for (int r = 0; r < 4; ++r) {
            const int s = mi * 16 + lg * 4 + r;
            const long gg = gbase + (long)s * gstride;
            const float rm = 1.0f - Mv[(int)(gg >> 6)];
            #pragma unroll
            for (int dj = 0; dj < 2; ++dj) {
                const int d = dj * 16 + l15;
                const size_t oidx = (size_t)gg * 512 + h * 32 + d;
                attout[oidx] = (bf16)(acc[mi][dj][r] + xin[oidx] * rm);
            }
        }
    }
}

// ---------------------------------------------------------------------------
// Host-side orchestration
// ---------------------------------------------------------------------------
extern "C" void kernel_launch(void* const* d_in, const int* in_sizes, int n_in,
                              void* d_out, int out_size, void* d_ws, size_t ws_size,
                              hipStream_t stream) {
    const float* x    = (const float*)d_in[0];
    const float* rpe0 = (const float*)d_in[1];
    const float* rpe1 = (const float*)d_in[2];
    auto W = [&](int i) { return (const float*)d_in[i]; };

    char* ws = (char*)d_ws;
    size_t off = 0;
    auto alloc = [&](size_t bytes) {
        void* p = ws + off;
        off += (bytes + 255) & ~(size_t)255;
        return p;
    };
    bf16 *wqkvT[2], *wprojT[2], *wfc1T[2], *wfc2T[2];
    for (int b = 0; b < 2; ++b) {
        wqkvT[b] = (bf16*)alloc((size_t)1536 * 512 * 2);
        wprojT[b] = (bf16*)alloc((size_t)512 * 512 * 2);
        wfc1T[b] = (bf16*)alloc((size_t)2048 * 512 * 2);
        wfc2T[b] = (bf16*)alloc((size_t)512 * 2048 * 2);
    }
    bf16* IMG = (bf16*)alloc((size_t)16384 * 512 * 2);
    bf16* QKV = (bf16*)alloc((size_t)16384 * 1536 * 2);
    bf16* ATT = (bf16*)alloc((size_t)16384 * 512 * 2);
    bf16* H1  = QKV;  // fc1 output [16384,2048] overlays QKV+ATT (both dead)
    float* X1    = (float*)alloc((size_t)16384 * 512 * 4);
    float* Mraw4 = (float*)alloc(1024 * 4);
    float* Mv    = (float*)alloc(256 * 4);
    float* XMID  = (float*)d_out;  // x after attention residual (fp32 spine)

    // ---- fused weight transpose: all 8 in one launch ----
    TransArgs ta;
    const int widx[8] = {5, 6, 10, 12, 16, 17, 21, 23};
    bf16* wdst[8] = {wqkvT[0], wprojT[0], wfc1T[0], wfc2T[0],
                     wqkvT[1], wprojT[1], wfc1T[1], wfc2T[1]};
    const int wk[8] = {512, 512, 512, 2048, 512, 512, 512, 2048};
    const int wn[8] = {1536, 512, 2048, 512, 1536, 512, 2048, 512};
    int acc_b = 0;
    for (int i = 0; i < 8; ++i) {
        ta.W[i] = W(widx[i]);
        ta.Wt[i] = wdst[i];
        ta.K[i] = wk[i];
        ta.N[i] = wn[i];
        ta.blk0[i] = acc_b;
        acc_b += (wn[i] / 32) * (wk[i] / 32);
    }
    ta.blk0[8] = acc_b;   // 6144
    transpose_all<<<acc_b, 256, 0, stream>>>(ta);

    for (int b = 0; b < 2; ++b) {
        const float* xin = (b == 0) ? x : X1;
        const float* rpe = (b == 0) ? rpe0 : rpe1;
        const int base = (b == 0) ? 3 : 14;
        const float* ln1g = W(base + 0);
        const float* ln1b = W(base + 1);
        const float* bproj = W(base + 4);
        const float* ln2g = W(base + 5);
        const float* ln2b = W(base + 6);
        const float* bfc1 = W(base + 8);
        const float* bfc2 = W(base + 10);

        // 1. LN1: xin -> IMG (bf16)
        ln_kernel<<<4096, 256, 0, stream>>>(xin, ln1g, ln1b, IMG);
        // 2. QKV GEMM (K=512 static): IMG @ wqkv -> QKV (bf16)
        gemm_bt<0, 512><<<dim3(12, 128), 512, 0, stream>>>(
            IMG, wqkvT[b], 1536, 512, nullptr, nullptr, nullptr, QKV);
        // 3-4. gating scalar M per window
        attn_stats<<<1024, 256, 0, stream>>>(QKV, rpe, Mraw4, b);
        mcalc<<<1, 256, 0, stream>>>(Mraw4, Mv);
        // 5. attention apply -> ATT (bf16), includes masked residual
        attn_apply<<<1024, 256, 0, stream>>>(QKV, rpe, Mv, xin, ATT, b);
        // 6. proj GEMM (K=512 static): ATT @ wproj + bproj + xin -> XMID
        gemm_bt<1, 512><<<dim3(4, 128), 512, 0, stream>>>(
            ATT, wprojT[b], 512, 512, bproj, xin, XMID, nullptr);
        // 7. LN2: XMID -> IMG (bf16)
        ln_kernel<<<4096, 256, 0, stream>>>(XMID, ln2g, ln2b, IMG);
        // 8. FC1 + exact GELU (K=512 static): IMG @ wfc1 -> H1 (bf16)
        gemm_bt<2, 512><<<dim3(16, 128), 512, 0, stream>>>(
            IMG, wfc1T[b], 2048, 512, bfc1, nullptr, nullptr, H1);
        // 9. FC2 (K=2048 runtime): H1 @ wfc2 + bfc2 + XMID
        gemm_bt<1, 0><<<dim3(4, 128), 512, 0, stream>>>(
            H1, wfc2T[b], 512, 2048, bfc2, XMID, (b == 0) ? X1 : XMID, nullptr);
    }
    (void)in_sizes; (void)n_in; (void)out_size; (void)ws_size;
}